// Round 9
// baseline (3056.262 us; speedup 1.0000x reference)
//
#include <hip/hip_runtime.h>

typedef unsigned int uint;
typedef unsigned short ushort;
typedef unsigned long long u64;

#define N_PTS 4096
#define B_SZ 16
#define M_PTS 1024
#define K_SMP 32
#define NROWS (B_SZ*M_PTS*K_SMP)   /* 524288 */
#define INV_CNT (1.0f/524288.0f)   /* exact: 2^-19 */

// ---------- helpers ----------
__device__ __forceinline__ float sqdist3(float ax,float ay,float az,float bx,float by,float bz){
  // exact-match of numpy/XLA f32: separate sub/mul/add, no FMA contraction
  float dx=__fsub_rn(ax,bx), dy=__fsub_rn(ay,by), dz=__fsub_rn(az,bz);
  return __fadd_rn(__fadd_rn(__fmul_rn(dx,dx),__fmul_rn(dy,dy)),__fmul_rn(dz,dz));
}
__device__ __forceinline__ ushort f2bf(float x){
  uint u = __float_as_uint(x);
  u = (u + 0x7fffu + ((u>>16)&1u)) >> 16;   // RNE
  return (ushort)u;
}
__device__ __forceinline__ float bf2f(uint u){ return __uint_as_float(u<<16); }

// ---------- FPS: key-only DPP argmax (r4 winner, 678us, restored verbatim) ----------
// key = (dist_bits<<32) | ~idx : unique, max == (largest dist, lowest idx)
__device__ __forceinline__ void kmerge(uint& kl, uint& kh, uint okl, uint okh){
  u64 a = ((u64)kh << 32) | kl;
  u64 b = ((u64)okh << 32) | okl;
  bool t = b > a;
  kl = t ? okl : kl;
  kh = t ? okh : kh;
}
template<int CTRL>
__device__ __forceinline__ uint dppu(uint v){
  return (uint)__builtin_amdgcn_update_dpp((int)v, (int)v, CTRL, 0xf, 0xf, false);
}
template<int CTRL>
__device__ __forceinline__ void dppkmerge(uint& kl, uint& kh){
  uint okl = dppu<CTRL>(kl);
  uint okh = dppu<CTRL>(kh);
  kmerge(kl, kh, okl, okh);
}

__global__ __launch_bounds__(512, 2) void fps_kernel(const float* __restrict__ xyz,
                                                     float* __restrict__ out_newxyz){
  const int b = blockIdx.x;
  const int t = threadIdx.x;
  __shared__ float4 sxyz[N_PTS];          // 64 KB: winner-coord fetch ONLY
  __shared__ uint   xch[2][8][2];         // per-wave winner keys, parity dbuf
  const float* src = xyz + (size_t)b*N_PTS*3;
  float px[8], py[8], pz[8], dist[8];
  uint nl[8];
#pragma unroll
  for (int i=0;i<8;i++){
    const int p = t + 512*i;              // strided ownership -> coalesced loads
    float x = src[3*p+0], y = src[3*p+1], z = src[3*p+2];
    px[i]=x; py[i]=y; pz[i]=z;
    dist[i]=1e10f; nl[i] = ~(uint)p;
    sxyz[p] = make_float4(x, y, z, 0.f);  // conflict-free ds_write_b128
  }
  __syncthreads();
  float cx, cy, cz;
  { float4 c0 = sxyz[0]; cx=c0.x; cy=c0.y; cz=c0.z; }
  const int w = t >> 6, lane = t & 63;
  float* outx = out_newxyz + (size_t)b*M_PTS*3;
  for (int s = 0; s < M_PTS; ++s){
    if (t == 0){ outx[s*3+0]=cx; outx[s*3+1]=cy; outx[s*3+2]=cz; }
    uint khv[8];
#pragma unroll
    for (int i=0;i<8;i++){
      float d  = sqdist3(px[i],py[i],pz[i],cx,cy,cz);
      float nd = fminf(dist[i], d);
      dist[i] = nd;
      khv[i] = __float_as_uint(nd);
    }
    uint l0=nl[0], h0=khv[0]; kmerge(l0,h0,nl[1],khv[1]);
    uint l1=nl[2], h1=khv[2]; kmerge(l1,h1,nl[3],khv[3]);
    uint l2=nl[4], h2=khv[4]; kmerge(l2,h2,nl[5],khv[5]);
    uint l3=nl[6], h3=khv[6]; kmerge(l3,h3,nl[7],khv[7]);
    kmerge(l0,h0,l1,h1); kmerge(l2,h2,l3,h3); kmerge(l0,h0,l2,h2);
    uint al=l0, ah=h0;
    dppkmerge<0x111>(al, ah);   // row_shr:1
    dppkmerge<0x112>(al, ah);   // row_shr:2
    dppkmerge<0x114>(al, ah);   // row_shr:4
    dppkmerge<0x118>(al, ah);   // row_shr:8
    dppkmerge<0x142>(al, ah);   // row_bcast:15
    dppkmerge<0x143>(al, ah);   // row_bcast:31
    const int par = s & 1;
    if (lane == 63){ xch[par][w][0] = al; xch[par][w][1] = ah; }
    __syncthreads();
    uint ckl = xch[par][lane & 7][0];
    uint ckh = xch[par][lane & 7][1];
    dppkmerge<0x111>(ckl, ckh);
    dppkmerge<0x112>(ckl, ckh);
    dppkmerge<0x114>(ckl, ckh);   // lane 7 (each row) = global winner
    uint wkl = (uint)__builtin_amdgcn_readlane((int)ckl, 7);
    uint idx = ~wkl;
    float4 cc = sxyz[idx];        // uniform broadcast read
    cx = cc.x; cy = cc.y; cz = cc.z;
  }
}

// ---------- 2. ball query (exact f32, first-32 in index order) ----------
__global__ __launch_bounds__(256) void ballq_kernel(const float* __restrict__ xyz,
                                                    const float* __restrict__ newxyz,
                                                    int* __restrict__ gidx){
  const int blk = blockIdx.x;
  const int b = blk >> 6;
  const int mbase = (blk & 63) * 16;
  __shared__ float sx[N_PTS], sy[N_PTS], sz[N_PTS];
  const float* src = xyz + (size_t)b*N_PTS*3;
  for (int i = threadIdx.x; i < N_PTS*3; i += 256){
    float v = src[i]; int p = i/3, j = i%3;
    (j==0?sx:(j==1?sy:sz))[p] = v;
  }
  __syncthreads();
  const int w = threadIdx.x >> 6, lane = threadIdx.x & 63;
  const float R2 = (float)(0.2*0.2);   // f32(f64 product) — matches reference cast
  for (int mm = w; mm < 16; mm += 4){
    const int m = mbase + mm;
    const float* c = newxyz + ((size_t)b*M_PTS + m)*3;
    float cx = c[0], cy = c[1], cz = c[2];
    int* gout = gidx + ((size_t)b*M_PTS + m)*K_SMP;
    int cnt = 0;
    for (int base = 0; base < N_PTS && cnt < K_SMP; base += 64){
      int p = base + lane;
      float d = sqdist3(sx[p],sy[p],sz[p],cx,cy,cz);
      bool in = (d <= R2);
      unsigned long long mask = __ballot(in);
      int prefix = __popcll(mask & ((1ull << lane) - 1ull));
      int slot = cnt + prefix;
      if (in && slot < K_SMP) gout[slot] = p;
      cnt += __popcll(mask);
    }
    if (cnt < K_SMP){
      int slot = cnt + lane;
      if (slot < K_SMP) gout[slot] = 0;
    }
  }
}

// ---------- 3. conv0: gather+concat + 67->64, W in LDS, 2 rows/thread ----------
__global__ __launch_bounds__(256, 2) void conv0_kernel(const float* __restrict__ xyz,
                                                       const float* __restrict__ points,
                                                       const float* __restrict__ newxyz,
                                                       const int* __restrict__ gidx,
                                                       const float* __restrict__ W0,
                                                       const float* __restrict__ b0,
                                                       ushort* __restrict__ x1){
  __shared__ float wlds[64*68];   // 17.4 KB, row pad to 68 floats (16B-aligned rows)
  __shared__ float sb[64];
  const int tid = threadIdx.x;
  for (int i = tid; i < 64*67; i += 256)
    wlds[(i/67)*68 + (i%67)] = W0[i];
  if (tid < 64) sb[tid] = b0[tid];
  __syncthreads();
  const int r0 = blockIdx.x*512 + tid;     // rows r0 and r0+256
  const int r1 = r0 + 256;
  float f0[67], f1[67];
  {
    const int b_ = r0 >> 15, m_ = (r0 >> 5) & 1023;
    const int g_ = gidx[r0];
    const float* pc = newxyz + ((size_t)(b_<<10) + m_)*3;
    const float* pp = xyz    + ((size_t)(b_<<12) + g_)*3;
    f0[0]=pp[0]-pc[0]; f0[1]=pp[1]-pc[1]; f0[2]=pp[2]-pc[2];
    const float4* prow = (const float4*)(points + (((size_t)(b_<<12) + g_) << 6));
#pragma unroll
    for (int q=0;q<16;q++){
      float4 v = prow[q];
      f0[3+4*q]=v.x; f0[4+4*q]=v.y; f0[5+4*q]=v.z; f0[6+4*q]=v.w;
    }
  }
  {
    const int b_ = r1 >> 15, m_ = (r1 >> 5) & 1023;
    const int g_ = gidx[r1];
    const float* pc = newxyz + ((size_t)(b_<<10) + m_)*3;
    const float* pp = xyz    + ((size_t)(b_<<12) + g_)*3;
    f1[0]=pp[0]-pc[0]; f1[1]=pp[1]-pc[1]; f1[2]=pp[2]-pc[2];
    const float4* prow = (const float4*)(points + (((size_t)(b_<<12) + g_) << 6));
#pragma unroll
    for (int q=0;q<16;q++){
      float4 v = prow[q];
      f1[3+4*q]=v.x; f1[4+4*q]=v.y; f1[5+4*q]=v.z; f1[6+4*q]=v.w;
    }
  }
  uint4* orow0 = (uint4*)(x1 + ((size_t)r0 << 6));
  uint4* orow1 = (uint4*)(x1 + ((size_t)r1 << 6));
#pragma unroll
  for (int ob=0; ob<8; ++ob){              // 8 channel-groups of 8
    float o0[8], o1[8];
#pragma unroll
    for (int j=0;j<8;j++){
      const int o = ob*8+j;
      const float4* w4 = (const float4*)(wlds + o*68);
      float a0 = sb[o], a1 = sb[o];
#pragma unroll
      for (int cq=0;cq<16;cq++){
        float4 wv = w4[cq];
        a0 = fmaf(f0[4*cq+0], wv.x, a0); a1 = fmaf(f1[4*cq+0], wv.x, a1);
        a0 = fmaf(f0[4*cq+1], wv.y, a0); a1 = fmaf(f1[4*cq+1], wv.y, a1);
        a0 = fmaf(f0[4*cq+2], wv.z, a0); a1 = fmaf(f1[4*cq+2], wv.z, a1);
        a0 = fmaf(f0[4*cq+3], wv.w, a0); a1 = fmaf(f1[4*cq+3], wv.w, a1);
      }
      float4 wt = w4[16];                  // cols 64..66 (+pad)
      a0 = fmaf(f0[64], wt.x, a0); a1 = fmaf(f1[64], wt.x, a1);
      a0 = fmaf(f0[65], wt.y, a0); a1 = fmaf(f1[65], wt.y, a1);
      a0 = fmaf(f0[66], wt.z, a0); a1 = fmaf(f1[66], wt.z, a1);
      o0[j]=a0; o1[j]=a1;
    }
    uint4 v0, v1;
    v0.x = (uint)f2bf(o0[0]) | ((uint)f2bf(o0[1])<<16);
    v0.y = (uint)f2bf(o0[2]) | ((uint)f2bf(o0[3])<<16);
    v0.z = (uint)f2bf(o0[4]) | ((uint)f2bf(o0[5])<<16);
    v0.w = (uint)f2bf(o0[6]) | ((uint)f2bf(o0[7])<<16);
    v1.x = (uint)f2bf(o1[0]) | ((uint)f2bf(o1[1])<<16);
    v1.y = (uint)f2bf(o1[2]) | ((uint)f2bf(o1[3])<<16);
    v1.z = (uint)f2bf(o1[4]) | ((uint)f2bf(o1[5])<<16);
    v1.w = (uint)f2bf(o1[6]) | ((uint)f2bf(o1[7])<<16);
    orow0[ob] = v0;
    orow1[ob] = v1;
  }
}

// ---------- stats: per-channel sum & sumsq, vectorized 8 ch/thread ----------
template<int C>
__global__ __launch_bounds__(256) void stats_kernel(const ushort* __restrict__ x,
                                                    float* __restrict__ S,
                                                    float* __restrict__ SS){
  constexpr int GRP = C/8;            // 8-channel groups per row: 8 (C=64) / 16 (C=128)
  constexpr int RL  = 256/GRP;        // row lanes per block: 32 / 16
  const int cg = threadIdx.x % GRP;
  const int rl = threadIdx.x / GRP;
  const int rows_per_block = NROWS / 1024;   // grid = 1024
  const int r0 = blockIdx.x * rows_per_block;
  float s[8], ss[8];
#pragma unroll
  for (int j=0;j<8;j++){ s[j]=0.f; ss[j]=0.f; }
  for (int r = r0 + rl; r < r0 + rows_per_block; r += RL){
    uint4 v = *(const uint4*)(x + (size_t)r*C + cg*8);
    uint d[4] = {v.x, v.y, v.z, v.w};
#pragma unroll
    for (int q=0;q<4;q++){
      float a0 = bf2f(d[q] & 0xffffu), a1 = bf2f(d[q] >> 16);
      s[2*q]   += a0; ss[2*q]   = fmaf(a0, a0, ss[2*q]);
      s[2*q+1] += a1; ss[2*q+1] = fmaf(a1, a1, ss[2*q+1]);
    }
  }
  __shared__ float ls[256][8], lss[256][8];   // 16 KB
#pragma unroll
  for (int j=0;j<8;j++){ ls[threadIdx.x][j]=s[j]; lss[threadIdx.x][j]=ss[j]; }
  __syncthreads();
  if (threadIdx.x < C){
    const int grp = threadIdx.x >> 3, j = threadIdx.x & 7;
    float a = 0.f, q2 = 0.f;
#pragma unroll
    for (int q = 0; q < RL; q++){ a += ls[q*GRP + grp][j]; q2 += lss[q*GRP + grp][j]; }
    atomicAdd(&S[threadIdx.x], a); atomicAdd(&SS[threadIdx.x], q2);
  }
}

// ---------- conv1: BN0+ReLU on read, 64->64, W in LDS, 2 rows/thread ----------
__global__ __launch_bounds__(256, 2) void conv1_kernel(const ushort* __restrict__ x1,
                                                       const float* __restrict__ S0,
                                                       const float* __restrict__ SS0,
                                                       const float* __restrict__ g0,
                                                       const float* __restrict__ be0,
                                                       const float* __restrict__ W1,
                                                       const float* __restrict__ b1,
                                                       ushort* __restrict__ x2){
  __shared__ float wlds[64*64];   // 16 KB
  __shared__ float sb[64], sc[64], sh[64];
  const int tid = threadIdx.x;
  {
    float4* w4 = (float4*)wlds;
    const float4* g4 = (const float4*)W1;
    for (int i = tid; i < 64*64/4; i += 256) w4[i] = g4[i];
  }
  if (tid < 64){
    int c = tid;
    sb[c] = b1[c];
    float mean = S0[c]*INV_CNT;
    float var  = fmaf(-mean, mean, SS0[c]*INV_CNT);
    float is   = rsqrtf(var + 1e-5f);
    float scv  = g0[c]*is;
    sc[c] = scv; sh[c] = fmaf(-mean, scv, be0[c]);
  }
  __syncthreads();
  const size_t r0 = (size_t)blockIdx.x*512 + tid;
  const size_t r1 = r0 + 256;
  float f0[64], f1[64];
  {
    const uint4* row = (const uint4*)(x1 + (r0<<6));
#pragma unroll
    for (int q=0;q<8;q++){
      uint4 v = row[q];
      f0[q*8+0]=bf2f(v.x&0xffffu); f0[q*8+1]=bf2f(v.x>>16);
      f0[q*8+2]=bf2f(v.y&0xffffu); f0[q*8+3]=bf2f(v.y>>16);
      f0[q*8+4]=bf2f(v.z&0xffffu); f0[q*8+5]=bf2f(v.z>>16);
      f0[q*8+6]=bf2f(v.w&0xffffu); f0[q*8+7]=bf2f(v.w>>16);
    }
    const uint4* row1 = (const uint4*)(x1 + (r1<<6));
#pragma unroll
    for (int q=0;q<8;q++){
      uint4 v = row1[q];
      f1[q*8+0]=bf2f(v.x&0xffffu); f1[q*8+1]=bf2f(v.x>>16);
      f1[q*8+2]=bf2f(v.y&0xffffu); f1[q*8+3]=bf2f(v.y>>16);
      f1[q*8+4]=bf2f(v.z&0xffffu); f1[q*8+5]=bf2f(v.z>>16);
      f1[q*8+6]=bf2f(v.w&0xffffu); f1[q*8+7]=bf2f(v.w>>16);
    }
  }
#pragma unroll
  for (int c=0;c<64;c++){
    f0[c] = fmaxf(fmaf(f0[c], sc[c], sh[c]), 0.f);
    f1[c] = fmaxf(fmaf(f1[c], sc[c], sh[c]), 0.f);
  }
  uint4* orow0 = (uint4*)(x2 + (r0<<6));
  uint4* orow1 = (uint4*)(x2 + (r1<<6));
#pragma unroll
  for (int ob=0; ob<8; ++ob){
    float o0[8], o1[8];
#pragma unroll
    for (int j=0;j<8;j++){
      const int o = ob*8+j;
      const float4* w4 = (const float4*)(wlds + o*64);
      float a0 = sb[o], a1 = sb[o];
#pragma unroll
      for (int cq=0;cq<16;cq++){
        float4 wv = w4[cq];
        a0 = fmaf(f0[4*cq+0], wv.x, a0); a1 = fmaf(f1[4*cq+0], wv.x, a1);
        a0 = fmaf(f0[4*cq+1], wv.y, a0); a1 = fmaf(f1[4*cq+1], wv.y, a1);
        a0 = fmaf(f0[4*cq+2], wv.z, a0); a1 = fmaf(f1[4*cq+2], wv.z, a1);
        a0 = fmaf(f0[4*cq+3], wv.w, a0); a1 = fmaf(f1[4*cq+3], wv.w, a1);
      }
      o0[j]=a0; o1[j]=a1;
    }
    uint4 v0, v1;
    v0.x = (uint)f2bf(o0[0]) | ((uint)f2bf(o0[1])<<16);
    v0.y = (uint)f2bf(o0[2]) | ((uint)f2bf(o0[3])<<16);
    v0.z = (uint)f2bf(o0[4]) | ((uint)f2bf(o0[5])<<16);
    v0.w = (uint)f2bf(o0[6]) | ((uint)f2bf(o0[7])<<16);
    v1.x = (uint)f2bf(o1[0]) | ((uint)f2bf(o1[1])<<16);
    v1.y = (uint)f2bf(o1[2]) | ((uint)f2bf(o1[3])<<16);
    v1.z = (uint)f2bf(o1[4]) | ((uint)f2bf(o1[5])<<16);
    v1.w = (uint)f2bf(o1[6]) | ((uint)f2bf(o1[7])<<16);
    orow0[ob] = v0;
    orow1[ob] = v1;
  }
}

// ---------- conv2: BN1+ReLU on read, 64->128, W in LDS, 2 rows/thread ----------
__global__ __launch_bounds__(256, 2) void conv2_kernel(const ushort* __restrict__ x2,
                                                       const float* __restrict__ S1,
                                                       const float* __restrict__ SS1,
                                                       const float* __restrict__ g1,
                                                       const float* __restrict__ be1,
                                                       const float* __restrict__ W2,
                                                       const float* __restrict__ b2,
                                                       ushort* __restrict__ x3){
  __shared__ float wlds[128*64];  // 32 KB
  __shared__ float sb[128], sc[64], sh[64];
  const int tid = threadIdx.x;
  {
    float4* w4 = (float4*)wlds;
    const float4* g4 = (const float4*)W2;
    for (int i = tid; i < 128*64/4; i += 256) w4[i] = g4[i];
  }
  if (tid < 128) sb[tid] = b2[tid];
  if (tid < 64){
    int c = tid;
    float mean = S1[c]*INV_CNT;
    float var  = fmaf(-mean, mean, SS1[c]*INV_CNT);
    float is   = rsqrtf(var + 1e-5f);
    float scv  = g1[c]*is;
    sc[c] = scv; sh[c] = fmaf(-mean, scv, be1[c]);
  }
  __syncthreads();
  const size_t r0 = (size_t)blockIdx.x*512 + tid;
  const size_t r1 = r0 + 256;
  float f0[64], f1[64];
  {
    const uint4* row = (const uint4*)(x2 + (r0<<6));
#pragma unroll
    for (int q=0;q<8;q++){
      uint4 v = row[q];
      f0[q*8+0]=bf2f(v.x&0xffffu); f0[q*8+1]=bf2f(v.x>>16);
      f0[q*8+2]=bf2f(v.y&0xffffu); f0[q*8+3]=bf2f(v.y>>16);
      f0[q*8+4]=bf2f(v.z&0xffffu); f0[q*8+5]=bf2f(v.z>>16);
      f0[q*8+6]=bf2f(v.w&0xffffu); f0[q*8+7]=bf2f(v.w>>16);
    }
    const uint4* row1 = (const uint4*)(x2 + (r1<<6));
#pragma unroll
    for (int q=0;q<8;q++){
      uint4 v = row1[q];
      f1[q*8+0]=bf2f(v.x&0xffffu); f1[q*8+1]=bf2f(v.x>>16);
      f1[q*8+2]=bf2f(v.y&0xffffu); f1[q*8+3]=bf2f(v.y>>16);
      f1[q*8+4]=bf2f(v.z&0xffffu); f1[q*8+5]=bf2f(v.z>>16);
      f1[q*8+6]=bf2f(v.w&0xffffu); f1[q*8+7]=bf2f(v.w>>16);
    }
  }
#pragma unroll
  for (int c=0;c<64;c++){
    f0[c] = fmaxf(fmaf(f0[c], sc[c], sh[c]), 0.f);
    f1[c] = fmaxf(fmaf(f1[c], sc[c], sh[c]), 0.f);
  }
  uint4* orow0 = (uint4*)(x3 + (r0<<7));
  uint4* orow1 = (uint4*)(x3 + (r1<<7));
#pragma unroll
  for (int ob=0; ob<16; ++ob){              // 16 channel-groups of 8 (128 out)
    float o0[8], o1[8];
#pragma unroll
    for (int j=0;j<8;j++){
      const int o = ob*8+j;
      const float4* w4 = (const float4*)(wlds + o*64);
      float a0 = sb[o], a1 = sb[o];
#pragma unroll
      for (int cq=0;cq<16;cq++){
        float4 wv = w4[cq];
        a0 = fmaf(f0[4*cq+0], wv.x, a0); a1 = fmaf(f1[4*cq+0], wv.x, a1);
        a0 = fmaf(f0[4*cq+1], wv.y, a0); a1 = fmaf(f1[4*cq+1], wv.y, a1);
        a0 = fmaf(f0[4*cq+2], wv.z, a0); a1 = fmaf(f1[4*cq+2], wv.z, a1);
        a0 = fmaf(f0[4*cq+3], wv.w, a0); a1 = fmaf(f1[4*cq+3], wv.w, a1);
      }
      o0[j]=a0; o1[j]=a1;
    }
    uint4 v0, v1;
    v0.x = (uint)f2bf(o0[0]) | ((uint)f2bf(o0[1])<<16);
    v0.y = (uint)f2bf(o0[2]) | ((uint)f2bf(o0[3])<<16);
    v0.z = (uint)f2bf(o0[4]) | ((uint)f2bf(o0[5])<<16);
    v0.w = (uint)f2bf(o0[6]) | ((uint)f2bf(o0[7])<<16);
    v1.x = (uint)f2bf(o1[0]) | ((uint)f2bf(o1[1])<<16);
    v1.y = (uint)f2bf(o1[2]) | ((uint)f2bf(o1[3])<<16);
    v1.z = (uint)f2bf(o1[4]) | ((uint)f2bf(o1[5])<<16);
    v1.w = (uint)f2bf(o1[6]) | ((uint)f2bf(o1[7])<<16);
    orow0[ob] = v0;
    orow1[ob] = v1;
  }
}

// ---------- BN2+ReLU + maxpool over K ----------
__global__ __launch_bounds__(256) void maxpool_kernel(const ushort* __restrict__ x3,
                                                      const float* __restrict__ S2,
                                                      const float* __restrict__ SS2,
                                                      const float* __restrict__ g2,
                                                      const float* __restrict__ be2,
                                                      float* __restrict__ outp){
  const int lane = threadIdx.x & 63, wv = threadIdx.x >> 6;
  const int bm = blockIdx.x*4 + wv;           // 16384 (b,m) groups
  const int c0 = lane*2, c1 = c0+1;
  float mean0 = S2[c0]*INV_CNT;
  float var0  = fmaf(-mean0, mean0, SS2[c0]*INV_CNT);
  float s0 = g2[c0]*rsqrtf(var0+1e-5f);
  float h0 = fmaf(-mean0, s0, be2[c0]);
  float mean1 = S2[c1]*INV_CNT;
  float var1  = fmaf(-mean1, mean1, SS2[c1]*INV_CNT);
  float s1 = g2[c1]*rsqrtf(var1+1e-5f);
  float h1 = fmaf(-mean1, s1, be2[c1]);
  const uint* rb = (const uint*)(x3 + (size_t)bm*K_SMP*128);
  float mx0 = 0.f, mx1 = 0.f;                 // relu floor
#pragma unroll
  for (int k=0;k<K_SMP;k++){
    uint v = rb[k*64 + lane];
    float a0 = bf2f(v & 0xffffu), a1 = bf2f(v >> 16);
    mx0 = fmaxf(mx0, fmaxf(fmaf(a0, s0, h0), 0.f));
    mx1 = fmaxf(mx1, fmaxf(fmaf(a1, s1, h1), 0.f));
  }
  float2* o2 = (float2*)(outp + (size_t)bm*128);
  o2[lane] = make_float2(mx0, mx1);
}

// ---------- launch ----------
extern "C" void kernel_launch(void* const* d_in, const int* in_sizes, int n_in,
                              void* d_out, int out_size, void* d_ws, size_t ws_size,
                              hipStream_t stream){
  const float* xyz    = (const float*)d_in[0];
  const float* points = (const float*)d_in[1];
  const float* w0  = (const float*)d_in[2];
  const float* b0  = (const float*)d_in[3];
  const float* g0  = (const float*)d_in[4];
  const float* be0 = (const float*)d_in[5];
  const float* w1  = (const float*)d_in[6];
  const float* b1  = (const float*)d_in[7];
  const float* g1  = (const float*)d_in[8];
  const float* be1 = (const float*)d_in[9];
  const float* w2  = (const float*)d_in[10];
  const float* b2  = (const float*)d_in[11];
  const float* g2  = (const float*)d_in[12];
  const float* be2 = (const float*)d_in[13];

  float* out      = (float*)d_out;
  float* newxyz   = out;                        // [16,1024,3]
  float* outp     = out + (size_t)B_SZ*M_PTS*3; // [16,1024,128]

  char* ws = (char*)d_ws;
  int*   gidx  = (int*)ws;
  float* stats = (float*)(ws + (2u<<20));
  float* S0 = stats,      *SS0 = stats+64;
  float* S1 = stats+128,  *SS1 = stats+192;
  float* S2 = stats+256,  *SS2 = stats+384;
  ushort* x1 = (ushort*)(ws + (4u<<20));
  ushort* x3 = (ushort*)(ws + (4u<<20));
  ushort* x2 = (ushort*)(ws + (4u<<20) + 134217728u);

  hipMemsetAsync(stats, 0, 512*sizeof(float), stream);
  fps_kernel  <<<B_SZ, 512, 0, stream>>>(xyz, newxyz);
  ballq_kernel<<<1024, 256, 0, stream>>>(xyz, newxyz, gidx);
  conv0_kernel<<<NROWS/512, 256, 0, stream>>>(xyz, points, newxyz, gidx, w0, b0, x1);
  stats_kernel<64><<<1024, 256, 0, stream>>>(x1, S0, SS0);
  conv1_kernel<<<NROWS/512, 256, 0, stream>>>(x1, S0, SS0, g0, be0, w1, b1, x2);
  stats_kernel<64><<<1024, 256, 0, stream>>>(x2, S1, SS1);
  conv2_kernel<<<NROWS/512, 256, 0, stream>>>(x2, S1, SS1, g1, be1, w2, b2, x3);
  stats_kernel<128><<<1024, 256, 0, stream>>>(x3, S2, SS2);
  maxpool_kernel<<<NROWS/128, 256, 0, stream>>>(x3, S2, SS2, g2, be2, outp);
}

// Round 10
// 1121.690 us; speedup vs baseline: 2.7247x; 2.7247x over previous
//
#include <hip/hip_runtime.h>

typedef unsigned int uint;
typedef unsigned short ushort;
typedef unsigned long long u64;

#define N_PTS 4096
#define B_SZ 16
#define M_PTS 1024
#define K_SMP 32
#define NROWS (B_SZ*M_PTS*K_SMP)   /* 524288 */
#define INV_CNT (1.0f/524288.0f)   /* exact: 2^-19 */

// ---------- helpers ----------
__device__ __forceinline__ float sqdist3(float ax,float ay,float az,float bx,float by,float bz){
  // exact-match of numpy/XLA f32: separate sub/mul/add, no FMA contraction
  float dx=__fsub_rn(ax,bx), dy=__fsub_rn(ay,by), dz=__fsub_rn(az,bz);
  return __fadd_rn(__fadd_rn(__fmul_rn(dx,dx),__fmul_rn(dy,dy)),__fmul_rn(dz,dz));
}
__device__ __forceinline__ ushort f2bf(float x){
  uint u = __float_as_uint(x);
  u = (u + 0x7fffu + ((u>>16)&1u)) >> 16;   // RNE
  return (ushort)u;
}
__device__ __forceinline__ float bf2f(uint u){ return __uint_as_float(u<<16); }

// ---------- FPS: key-only DPP argmax (r4 winner, 678us) ----------
__device__ __forceinline__ void kmerge(uint& kl, uint& kh, uint okl, uint okh){
  u64 a = ((u64)kh << 32) | kl;
  u64 b = ((u64)okh << 32) | okl;
  bool t = b > a;
  kl = t ? okl : kl;
  kh = t ? okh : kh;
}
template<int CTRL>
__device__ __forceinline__ uint dppu(uint v){
  return (uint)__builtin_amdgcn_update_dpp((int)v, (int)v, CTRL, 0xf, 0xf, false);
}
template<int CTRL>
__device__ __forceinline__ void dppkmerge(uint& kl, uint& kh){
  uint okl = dppu<CTRL>(kl);
  uint okh = dppu<CTRL>(kh);
  kmerge(kl, kh, okl, okh);
}

__global__ __launch_bounds__(512, 2) void fps_kernel(const float* __restrict__ xyz,
                                                     float* __restrict__ out_newxyz){
  const int b = blockIdx.x;
  const int t = threadIdx.x;
  __shared__ float4 sxyz[N_PTS];          // 64 KB: winner-coord fetch ONLY
  __shared__ uint   xch[2][8][2];         // per-wave winner keys, parity dbuf
  const float* src = xyz + (size_t)b*N_PTS*3;
  float px[8], py[8], pz[8], dist[8];
  uint nl[8];
#pragma unroll
  for (int i=0;i<8;i++){
    const int p = t + 512*i;              // strided ownership -> coalesced loads
    float x = src[3*p+0], y = src[3*p+1], z = src[3*p+2];
    px[i]=x; py[i]=y; pz[i]=z;
    dist[i]=1e10f; nl[i] = ~(uint)p;
    sxyz[p] = make_float4(x, y, z, 0.f);  // conflict-free ds_write_b128
  }
  __syncthreads();
  float cx, cy, cz;
  { float4 c0 = sxyz[0]; cx=c0.x; cy=c0.y; cz=c0.z; }
  const int w = t >> 6, lane = t & 63;
  float* outx = out_newxyz + (size_t)b*M_PTS*3;
  for (int s = 0; s < M_PTS; ++s){
    if (t == 0){ outx[s*3+0]=cx; outx[s*3+1]=cy; outx[s*3+2]=cz; }
    uint khv[8];
#pragma unroll
    for (int i=0;i<8;i++){
      float d  = sqdist3(px[i],py[i],pz[i],cx,cy,cz);
      float nd = fminf(dist[i], d);
      dist[i] = nd;
      khv[i] = __float_as_uint(nd);
    }
    uint l0=nl[0], h0=khv[0]; kmerge(l0,h0,nl[1],khv[1]);
    uint l1=nl[2], h1=khv[2]; kmerge(l1,h1,nl[3],khv[3]);
    uint l2=nl[4], h2=khv[4]; kmerge(l2,h2,nl[5],khv[5]);
    uint l3=nl[6], h3=khv[6]; kmerge(l3,h3,nl[7],khv[7]);
    kmerge(l0,h0,l1,h1); kmerge(l2,h2,l3,h3); kmerge(l0,h0,l2,h2);
    uint al=l0, ah=h0;
    dppkmerge<0x111>(al, ah);   // row_shr:1
    dppkmerge<0x112>(al, ah);   // row_shr:2
    dppkmerge<0x114>(al, ah);   // row_shr:4
    dppkmerge<0x118>(al, ah);   // row_shr:8
    dppkmerge<0x142>(al, ah);   // row_bcast:15
    dppkmerge<0x143>(al, ah);   // row_bcast:31
    const int par = s & 1;
    if (lane == 63){ xch[par][w][0] = al; xch[par][w][1] = ah; }
    __syncthreads();
    uint ckl = xch[par][lane & 7][0];
    uint ckh = xch[par][lane & 7][1];
    dppkmerge<0x111>(ckl, ckh);
    dppkmerge<0x112>(ckl, ckh);
    dppkmerge<0x114>(ckl, ckh);   // lane 7 (each row) = global winner
    uint wkl = (uint)__builtin_amdgcn_readlane((int)ckl, 7);
    uint idx = ~wkl;
    float4 cc = sxyz[idx];        // uniform broadcast read
    cx = cc.x; cy = cc.y; cz = cc.z;
  }
}

// ---------- 2. ball query (exact f32, first-32 in index order) ----------
__global__ __launch_bounds__(256) void ballq_kernel(const float* __restrict__ xyz,
                                                    const float* __restrict__ newxyz,
                                                    int* __restrict__ gidx){
  const int blk = blockIdx.x;
  const int b = blk >> 6;
  const int mbase = (blk & 63) * 16;
  __shared__ float sx[N_PTS], sy[N_PTS], sz[N_PTS];
  const float* src = xyz + (size_t)b*N_PTS*3;
  for (int i = threadIdx.x; i < N_PTS*3; i += 256){
    float v = src[i]; int p = i/3, j = i%3;
    (j==0?sx:(j==1?sy:sz))[p] = v;
  }
  __syncthreads();
  const int w = threadIdx.x >> 6, lane = threadIdx.x & 63;
  const float R2 = (float)(0.2*0.2);   // f32(f64 product) — matches reference cast
  for (int mm = w; mm < 16; mm += 4){
    const int m = mbase + mm;
    const float* c = newxyz + ((size_t)b*M_PTS + m)*3;
    float cx = c[0], cy = c[1], cz = c[2];
    int* gout = gidx + ((size_t)b*M_PTS + m)*K_SMP;
    int cnt = 0;
    for (int base = 0; base < N_PTS && cnt < K_SMP; base += 64){
      int p = base + lane;
      float d = sqdist3(sx[p],sy[p],sz[p],cx,cy,cz);
      bool in = (d <= R2);
      unsigned long long mask = __ballot(in);
      int prefix = __popcll(mask & ((1ull << lane) - 1ull));
      int slot = cnt + prefix;
      if (in && slot < K_SMP) gout[slot] = p;
      cnt += __popcll(mask);
    }
    if (cnt < K_SMP){
      int slot = cnt + lane;
      if (slot < K_SMP) gout[slot] = 0;
    }
  }
}

// ---------- conv0: LDS-tiled GEMM, 64 rows x 64 outs, K=67, gather fill ----------
// thread (tr,tc) owns a 4x4 accumulator tile -> no spills (acc=16 regs)
__global__ __launch_bounds__(256) void conv0_kernel(const float* __restrict__ xyz,
                                                    const float* __restrict__ points,
                                                    const float* __restrict__ newxyz,
                                                    const int* __restrict__ gidx,
                                                    const float* __restrict__ W0,
                                                    const float* __restrict__ b0,
                                                    ushort* __restrict__ x1){
  __shared__ float A [67][68];     // [k][row]  18.2 KB (pitch 68 breaks bank aliasing)
  __shared__ float Bw[67][68];     // [k][out]
  __shared__ float sb[64];
  const int tid = threadIdx.x;
  if (tid < 64) sb[tid] = b0[tid];
  for (int idx = tid; idx < 64*67; idx += 256){
    int o = idx / 67, k = idx - o*67;
    Bw[k][o] = W0[idx];
  }
  const size_t rbase = (size_t)blockIdx.x * 64;
  {
    const int r = tid & 63;
    const int q = tid >> 6;            // 0..3 quarters of the points row
    const int R = (int)rbase + r;
    const int b_ = R >> 15, m_ = (R >> 5) & 1023;
    const int g_ = gidx[R];
    const float4* p4 = (const float4*)(points + (((size_t)(b_<<12) + g_) << 6) + q*16);
#pragma unroll
    for (int j=0;j<4;j++){
      float4 v = p4[j];
      int c = 3 + q*16 + j*4;
      A[c+0][r]=v.x; A[c+1][r]=v.y; A[c+2][r]=v.z; A[c+3][r]=v.w;
    }
    if (q == 0){
      const float* pc = newxyz + ((size_t)(b_<<10) + m_)*3;
      const float* pp = xyz    + ((size_t)(b_<<12) + g_)*3;
      A[0][r] = pp[0]-pc[0];
      A[1][r] = pp[1]-pc[1];
      A[2][r] = pp[2]-pc[2];
    }
  }
  __syncthreads();
  const int tr = tid >> 4, tc = tid & 15;
  float acc[4][4];
#pragma unroll
  for (int i=0;i<4;i++)
#pragma unroll
    for (int j=0;j<4;j++) acc[i][j] = sb[tc*4+j];
#pragma unroll 4
  for (int k=0;k<67;k++){
    float4 a = *(const float4*)&A [k][tr*4];
    float4 w = *(const float4*)&Bw[k][tc*4];
    acc[0][0]=fmaf(a.x,w.x,acc[0][0]); acc[0][1]=fmaf(a.x,w.y,acc[0][1]);
    acc[0][2]=fmaf(a.x,w.z,acc[0][2]); acc[0][3]=fmaf(a.x,w.w,acc[0][3]);
    acc[1][0]=fmaf(a.y,w.x,acc[1][0]); acc[1][1]=fmaf(a.y,w.y,acc[1][1]);
    acc[1][2]=fmaf(a.y,w.z,acc[1][2]); acc[1][3]=fmaf(a.y,w.w,acc[1][3]);
    acc[2][0]=fmaf(a.z,w.x,acc[2][0]); acc[2][1]=fmaf(a.z,w.y,acc[2][1]);
    acc[2][2]=fmaf(a.z,w.z,acc[2][2]); acc[2][3]=fmaf(a.z,w.w,acc[2][3]);
    acc[3][0]=fmaf(a.w,w.x,acc[3][0]); acc[3][1]=fmaf(a.w,w.y,acc[3][1]);
    acc[3][2]=fmaf(a.w,w.z,acc[3][2]); acc[3][3]=fmaf(a.w,w.w,acc[3][3]);
  }
#pragma unroll
  for (int i=0;i<4;i++){
    uint2 v;
    v.x = (uint)f2bf(acc[i][0]) | ((uint)f2bf(acc[i][1])<<16);
    v.y = (uint)f2bf(acc[i][2]) | ((uint)f2bf(acc[i][3])<<16);
    *(uint2*)(x1 + ((rbase + tr*4 + i) << 6) + tc*4) = v;
  }
}

// ---------- convg: BN+ReLU on read, LDS-tiled GEMM 64x64, K=64 ----------
// OSTRIDE = output row stride (64 for conv1, 128 for conv2); blockIdx.y = col tile
template<int OSTRIDE>
__global__ __launch_bounds__(256) void convg_kernel(const ushort* __restrict__ xin,
                                                    const float* __restrict__ Sv,
                                                    const float* __restrict__ SSv,
                                                    const float* __restrict__ gg,
                                                    const float* __restrict__ be,
                                                    const float* __restrict__ W,
                                                    const float* __restrict__ bias,
                                                    ushort* __restrict__ xout){
  __shared__ float A [64][68];     // [k][row] BN+ReLU'd inputs, 17.4 KB
  __shared__ float Bw[64][68];     // [k][out]
  __shared__ float sc[64], sh[64], sb[64];
  const int tid = threadIdx.x;
  const int ocol0 = blockIdx.y * 64;
  if (tid < 64){
    int c = tid;
    float mean = Sv[c]*INV_CNT;
    float var  = fmaf(-mean, mean, SSv[c]*INV_CNT);
    float is   = rsqrtf(var + 1e-5f);
    float scv  = gg[c]*is;
    sc[c] = scv; sh[c] = fmaf(-mean, scv, be[c]);
    sb[c] = bias[ocol0 + c];
  }
  {
    const int o  = tid & 63;
    const int kq = tid >> 6;
    const float* wrow = W + (size_t)(ocol0 + o)*64;
#pragma unroll
    for (int kk=0;kk<4;kk++){
      int k = (kq + 4*kk)*4;
      float4 wv = *(const float4*)(wrow + k);
      Bw[k+0][o]=wv.x; Bw[k+1][o]=wv.y; Bw[k+2][o]=wv.z; Bw[k+3][o]=wv.w;
    }
  }
  __syncthreads();                  // sc/sh ready for A fill
  const size_t rbase = (size_t)blockIdx.x * 64;
  {
    const int r   = tid & 63;
    const int kg0 = tid >> 6;
#pragma unroll
    for (int kk=0;kk<2;kk++){
      const int kg = kg0 + 4*kk;    // 0..7 (8 bf16 each)
      uint4 v = *(const uint4*)(xin + ((rbase + r) << 6) + kg*8);
      uint d[4] = {v.x,v.y,v.z,v.w};
#pragma unroll
      for (int q=0;q<4;q++){
        int k = kg*8 + 2*q;
        float a0 = bf2f(d[q] & 0xffffu), a1 = bf2f(d[q] >> 16);
        A[k+0][r] = fmaxf(fmaf(a0, sc[k+0], sh[k+0]), 0.f);
        A[k+1][r] = fmaxf(fmaf(a1, sc[k+1], sh[k+1]), 0.f);
      }
    }
  }
  __syncthreads();
  const int tr = tid >> 4, tc = tid & 15;
  float acc[4][4];
#pragma unroll
  for (int i=0;i<4;i++)
#pragma unroll
    for (int j=0;j<4;j++) acc[i][j] = sb[tc*4+j];
#pragma unroll 4
  for (int k=0;k<64;k++){
    float4 a = *(const float4*)&A [k][tr*4];
    float4 w = *(const float4*)&Bw[k][tc*4];
    acc[0][0]=fmaf(a.x,w.x,acc[0][0]); acc[0][1]=fmaf(a.x,w.y,acc[0][1]);
    acc[0][2]=fmaf(a.x,w.z,acc[0][2]); acc[0][3]=fmaf(a.x,w.w,acc[0][3]);
    acc[1][0]=fmaf(a.y,w.x,acc[1][0]); acc[1][1]=fmaf(a.y,w.y,acc[1][1]);
    acc[1][2]=fmaf(a.y,w.z,acc[1][2]); acc[1][3]=fmaf(a.y,w.w,acc[1][3]);
    acc[2][0]=fmaf(a.z,w.x,acc[2][0]); acc[2][1]=fmaf(a.z,w.y,acc[2][1]);
    acc[2][2]=fmaf(a.z,w.z,acc[2][2]); acc[2][3]=fmaf(a.z,w.w,acc[2][3]);
    acc[3][0]=fmaf(a.w,w.x,acc[3][0]); acc[3][1]=fmaf(a.w,w.y,acc[3][1]);
    acc[3][2]=fmaf(a.w,w.z,acc[3][2]); acc[3][3]=fmaf(a.w,w.w,acc[3][3]);
  }
#pragma unroll
  for (int i=0;i<4;i++){
    uint2 v;
    v.x = (uint)f2bf(acc[i][0]) | ((uint)f2bf(acc[i][1])<<16);
    v.y = (uint)f2bf(acc[i][2]) | ((uint)f2bf(acc[i][3])<<16);
    *(uint2*)(xout + (rbase + tr*4 + i)*OSTRIDE + ocol0 + tc*4) = v;
  }
}

// ---------- stats: per-channel sum & sumsq, vectorized 8 ch/thread ----------
template<int C>
__global__ __launch_bounds__(256) void stats_kernel(const ushort* __restrict__ x,
                                                    float* __restrict__ S,
                                                    float* __restrict__ SS){
  constexpr int GRP = C/8;
  constexpr int RL  = 256/GRP;
  const int cg = threadIdx.x % GRP;
  const int rl = threadIdx.x / GRP;
  const int rows_per_block = NROWS / 1024;   // grid = 1024
  const int r0 = blockIdx.x * rows_per_block;
  float s[8], ss[8];
#pragma unroll
  for (int j=0;j<8;j++){ s[j]=0.f; ss[j]=0.f; }
  for (int r = r0 + rl; r < r0 + rows_per_block; r += RL){
    uint4 v = *(const uint4*)(x + (size_t)r*C + cg*8);
    uint d[4] = {v.x, v.y, v.z, v.w};
#pragma unroll
    for (int q=0;q<4;q++){
      float a0 = bf2f(d[q] & 0xffffu), a1 = bf2f(d[q] >> 16);
      s[2*q]   += a0; ss[2*q]   = fmaf(a0, a0, ss[2*q]);
      s[2*q+1] += a1; ss[2*q+1] = fmaf(a1, a1, ss[2*q+1]);
    }
  }
  __shared__ float ls[256][8], lss[256][8];
#pragma unroll
  for (int j=0;j<8;j++){ ls[threadIdx.x][j]=s[j]; lss[threadIdx.x][j]=ss[j]; }
  __syncthreads();
  if (threadIdx.x < C){
    const int grp = threadIdx.x >> 3, j = threadIdx.x & 7;
    float a = 0.f, q2 = 0.f;
#pragma unroll
    for (int q = 0; q < RL; q++){ a += ls[q*GRP + grp][j]; q2 += lss[q*GRP + grp][j]; }
    atomicAdd(&S[threadIdx.x], a); atomicAdd(&SS[threadIdx.x], q2);
  }
}

// ---------- BN2+ReLU + maxpool over K ----------
__global__ __launch_bounds__(256) void maxpool_kernel(const ushort* __restrict__ x3,
                                                      const float* __restrict__ S2,
                                                      const float* __restrict__ SS2,
                                                      const float* __restrict__ g2,
                                                      const float* __restrict__ be2,
                                                      float* __restrict__ outp){
  const int lane = threadIdx.x & 63, wv = threadIdx.x >> 6;
  const int bm = blockIdx.x*4 + wv;           // 16384 (b,m) groups
  const int c0 = lane*2, c1 = c0+1;
  float mean0 = S2[c0]*INV_CNT;
  float var0  = fmaf(-mean0, mean0, SS2[c0]*INV_CNT);
  float s0 = g2[c0]*rsqrtf(var0+1e-5f);
  float h0 = fmaf(-mean0, s0, be2[c0]);
  float mean1 = S2[c1]*INV_CNT;
  float var1  = fmaf(-mean1, mean1, SS2[c1]*INV_CNT);
  float s1 = g2[c1]*rsqrtf(var1+1e-5f);
  float h1 = fmaf(-mean1, s1, be2[c1]);
  const uint* rb = (const uint*)(x3 + (size_t)bm*K_SMP*128);
  float mx0 = 0.f, mx1 = 0.f;                 // relu floor
#pragma unroll
  for (int k=0;k<K_SMP;k++){
    uint v = rb[k*64 + lane];
    float a0 = bf2f(v & 0xffffu), a1 = bf2f(v >> 16);
    mx0 = fmaxf(mx0, fmaxf(fmaf(a0, s0, h0), 0.f));
    mx1 = fmaxf(mx1, fmaxf(fmaf(a1, s1, h1), 0.f));
  }
  float2* o2 = (float2*)(outp + (size_t)bm*128);
  o2[lane] = make_float2(mx0, mx1);
}

// ---------- launch ----------
extern "C" void kernel_launch(void* const* d_in, const int* in_sizes, int n_in,
                              void* d_out, int out_size, void* d_ws, size_t ws_size,
                              hipStream_t stream){
  const float* xyz    = (const float*)d_in[0];
  const float* points = (const float*)d_in[1];
  const float* w0  = (const float*)d_in[2];
  const float* b0  = (const float*)d_in[3];
  const float* g0  = (const float*)d_in[4];
  const float* be0 = (const float*)d_in[5];
  const float* w1  = (const float*)d_in[6];
  const float* b1  = (const float*)d_in[7];
  const float* g1  = (const float*)d_in[8];
  const float* be1 = (const float*)d_in[9];
  const float* w2  = (const float*)d_in[10];
  const float* b2  = (const float*)d_in[11];
  const float* g2  = (const float*)d_in[12];
  const float* be2 = (const float*)d_in[13];

  float* out      = (float*)d_out;
  float* newxyz   = out;                        // [16,1024,3]
  float* outp     = out + (size_t)B_SZ*M_PTS*3; // [16,1024,128]

  char* ws = (char*)d_ws;
  int*   gidx  = (int*)ws;
  float* stats = (float*)(ws + (2u<<20));
  float* S0 = stats,      *SS0 = stats+64;
  float* S1 = stats+128,  *SS1 = stats+192;
  float* S2 = stats+256,  *SS2 = stats+384;
  ushort* x1 = (ushort*)(ws + (4u<<20));
  ushort* x3 = (ushort*)(ws + (4u<<20));
  ushort* x2 = (ushort*)(ws + (4u<<20) + 134217728u);

  hipMemsetAsync(stats, 0, 512*sizeof(float), stream);
  fps_kernel  <<<B_SZ, 512, 0, stream>>>(xyz, newxyz);
  ballq_kernel<<<1024, 256, 0, stream>>>(xyz, newxyz, gidx);
  conv0_kernel<<<NROWS/64, 256, 0, stream>>>(xyz, points, newxyz, gidx, w0, b0, x1);
  stats_kernel<64><<<1024, 256, 0, stream>>>(x1, S0, SS0);
  convg_kernel<64><<<dim3(NROWS/64, 1), 256, 0, stream>>>(x1, S0, SS0, g0, be0, w1, b1, x2);
  stats_kernel<64><<<1024, 256, 0, stream>>>(x2, S1, SS1);
  convg_kernel<128><<<dim3(NROWS/64, 2), 256, 0, stream>>>(x2, S1, SS1, g1, be1, w2, b2, x3);
  stats_kernel<128><<<1024, 256, 0, stream>>>(x3, S2, SS2);
  maxpool_kernel<<<NROWS/128, 256, 0, stream>>>(x3, S2, SS2, g2, be2, outp);
}

// Round 11
// 1102.417 us; speedup vs baseline: 2.7723x; 1.0175x over previous
//
#include <hip/hip_runtime.h>

typedef unsigned int uint;
typedef unsigned short ushort;
typedef unsigned long long u64;

#define N_PTS 4096
#define B_SZ 16
#define M_PTS 1024
#define K_SMP 32
#define NROWS (B_SZ*M_PTS*K_SMP)   /* 524288 */
#define INV_CNT (1.0f/524288.0f)   /* exact: 2^-19 */

// ---------- helpers ----------
__device__ __forceinline__ float sqdist3(float ax,float ay,float az,float bx,float by,float bz){
  // exact-match of numpy/XLA f32: separate sub/mul/add, no FMA contraction
  float dx=__fsub_rn(ax,bx), dy=__fsub_rn(ay,by), dz=__fsub_rn(az,bz);
  return __fadd_rn(__fadd_rn(__fmul_rn(dx,dx),__fmul_rn(dy,dy)),__fmul_rn(dz,dz));
}
__device__ __forceinline__ ushort f2bf(float x){
  uint u = __float_as_uint(x);
  u = (u + 0x7fffu + ((u>>16)&1u)) >> 16;   // RNE
  return (ushort)u;
}
__device__ __forceinline__ float bf2f(uint u){ return __uint_as_float(u<<16); }

// ---------- FPS: key-only DPP argmax (r4 winner, 678us; structural floor) ----------
__device__ __forceinline__ void kmerge(uint& kl, uint& kh, uint okl, uint okh){
  u64 a = ((u64)kh << 32) | kl;
  u64 b = ((u64)okh << 32) | okl;
  bool t = b > a;
  kl = t ? okl : kl;
  kh = t ? okh : kh;
}
template<int CTRL>
__device__ __forceinline__ uint dppu(uint v){
  return (uint)__builtin_amdgcn_update_dpp((int)v, (int)v, CTRL, 0xf, 0xf, false);
}
template<int CTRL>
__device__ __forceinline__ void dppkmerge(uint& kl, uint& kh){
  uint okl = dppu<CTRL>(kl);
  uint okh = dppu<CTRL>(kh);
  kmerge(kl, kh, okl, okh);
}

__global__ __launch_bounds__(512, 2) void fps_kernel(const float* __restrict__ xyz,
                                                     float* __restrict__ out_newxyz){
  const int b = blockIdx.x;
  const int t = threadIdx.x;
  __shared__ float4 sxyz[N_PTS];          // 64 KB: winner-coord fetch ONLY
  __shared__ uint   xch[2][8][2];         // per-wave winner keys, parity dbuf
  const float* src = xyz + (size_t)b*N_PTS*3;
  float px[8], py[8], pz[8], dist[8];
  uint nl[8];
#pragma unroll
  for (int i=0;i<8;i++){
    const int p = t + 512*i;              // strided ownership -> coalesced loads
    float x = src[3*p+0], y = src[3*p+1], z = src[3*p+2];
    px[i]=x; py[i]=y; pz[i]=z;
    dist[i]=1e10f; nl[i] = ~(uint)p;
    sxyz[p] = make_float4(x, y, z, 0.f);  // conflict-free ds_write_b128
  }
  __syncthreads();
  float cx, cy, cz;
  { float4 c0 = sxyz[0]; cx=c0.x; cy=c0.y; cz=c0.z; }
  const int w = t >> 6, lane = t & 63;
  float* outx = out_newxyz + (size_t)b*M_PTS*3;
  for (int s = 0; s < M_PTS; ++s){
    if (t == 0){ outx[s*3+0]=cx; outx[s*3+1]=cy; outx[s*3+2]=cz; }
    uint khv[8];
#pragma unroll
    for (int i=0;i<8;i++){
      float d  = sqdist3(px[i],py[i],pz[i],cx,cy,cz);
      float nd = fminf(dist[i], d);
      dist[i] = nd;
      khv[i] = __float_as_uint(nd);
    }
    uint l0=nl[0], h0=khv[0]; kmerge(l0,h0,nl[1],khv[1]);
    uint l1=nl[2], h1=khv[2]; kmerge(l1,h1,nl[3],khv[3]);
    uint l2=nl[4], h2=khv[4]; kmerge(l2,h2,nl[5],khv[5]);
    uint l3=nl[6], h3=khv[6]; kmerge(l3,h3,nl[7],khv[7]);
    kmerge(l0,h0,l1,h1); kmerge(l2,h2,l3,h3); kmerge(l0,h0,l2,h2);
    uint al=l0, ah=h0;
    dppkmerge<0x111>(al, ah);   // row_shr:1
    dppkmerge<0x112>(al, ah);   // row_shr:2
    dppkmerge<0x114>(al, ah);   // row_shr:4
    dppkmerge<0x118>(al, ah);   // row_shr:8
    dppkmerge<0x142>(al, ah);   // row_bcast:15
    dppkmerge<0x143>(al, ah);   // row_bcast:31
    const int par = s & 1;
    if (lane == 63){ xch[par][w][0] = al; xch[par][w][1] = ah; }
    __syncthreads();
    uint ckl = xch[par][lane & 7][0];
    uint ckh = xch[par][lane & 7][1];
    dppkmerge<0x111>(ckl, ckh);
    dppkmerge<0x112>(ckl, ckh);
    dppkmerge<0x114>(ckl, ckh);   // lane 7 (each row) = global winner
    uint wkl = (uint)__builtin_amdgcn_readlane((int)ckl, 7);
    uint idx = ~wkl;
    float4 cc = sxyz[idx];        // uniform broadcast read
    cx = cc.x; cy = cc.y; cz = cc.z;
  }
}

// ---------- 2. ball query (exact f32, first-32 in index order) ----------
__global__ __launch_bounds__(256) void ballq_kernel(const float* __restrict__ xyz,
                                                    const float* __restrict__ newxyz,
                                                    int* __restrict__ gidx){
  const int blk = blockIdx.x;
  const int b = blk >> 6;
  const int mbase = (blk & 63) * 16;
  __shared__ float sx[N_PTS], sy[N_PTS], sz[N_PTS];
  const float* src = xyz + (size_t)b*N_PTS*3;
  for (int i = threadIdx.x; i < N_PTS*3; i += 256){
    float v = src[i]; int p = i/3, j = i%3;
    (j==0?sx:(j==1?sy:sz))[p] = v;
  }
  __syncthreads();
  const int w = threadIdx.x >> 6, lane = threadIdx.x & 63;
  const float R2 = (float)(0.2*0.2);   // f32(f64 product) — matches reference cast
  for (int mm = w; mm < 16; mm += 4){
    const int m = mbase + mm;
    const float* c = newxyz + ((size_t)b*M_PTS + m)*3;
    float cx = c[0], cy = c[1], cz = c[2];
    int* gout = gidx + ((size_t)b*M_PTS + m)*K_SMP;
    int cnt = 0;
    for (int base = 0; base < N_PTS && cnt < K_SMP; base += 64){
      int p = base + lane;
      float d = sqdist3(sx[p],sy[p],sz[p],cx,cy,cz);
      bool in = (d <= R2);
      unsigned long long mask = __ballot(in);
      int prefix = __popcll(mask & ((1ull << lane) - 1ull));
      int slot = cnt + prefix;
      if (in && slot < K_SMP) gout[slot] = p;
      cnt += __popcll(mask);
    }
    if (cnt < K_SMP){
      int slot = cnt + lane;
      if (slot < K_SMP) gout[slot] = 0;
    }
  }
}

// ---------- conv0: LDS-tiled GEMM, 128 rows x 64 outs, K=67, acc 8x4 ----------
__global__ __launch_bounds__(256, 2) void conv0_kernel(const float* __restrict__ xyz,
                                                       const float* __restrict__ points,
                                                       const float* __restrict__ newxyz,
                                                       const int* __restrict__ gidx,
                                                       const float* __restrict__ W0,
                                                       const float* __restrict__ b0,
                                                       ushort* __restrict__ x1){
  __shared__ float A [67][132];    // [k][row] 35.4 KB
  __shared__ float Bw[67][68];     // [k][out] 18.2 KB
  __shared__ float sb[64];
  const int tid = threadIdx.x;
  if (tid < 64) sb[tid] = b0[tid];
  for (int idx = tid; idx < 64*67; idx += 256){
    int o = idx / 67, k = idx - o*67;
    Bw[k][o] = W0[idx];
  }
  const size_t rbase = (size_t)blockIdx.x * 128;
  {
    const int r  = tid & 127;
    const int hf = tid >> 7;           // half of the 64 points-channels
    const int R = (int)rbase + r;
    const int b_ = R >> 15, m_ = (R >> 5) & 1023;
    const int g_ = gidx[R];
    const float4* p4 = (const float4*)(points + (((size_t)(b_<<12) + g_) << 6) + hf*32);
#pragma unroll
    for (int j=0;j<8;j++){
      float4 v = p4[j];
      int c = 3 + hf*32 + j*4;
      A[c+0][r]=v.x; A[c+1][r]=v.y; A[c+2][r]=v.z; A[c+3][r]=v.w;
    }
    if (hf == 0){
      const float* pc = newxyz + ((size_t)(b_<<10) + m_)*3;
      const float* pp = xyz    + ((size_t)(b_<<12) + g_)*3;
      A[0][r] = pp[0]-pc[0];
      A[1][r] = pp[1]-pc[1];
      A[2][r] = pp[2]-pc[2];
    }
  }
  __syncthreads();
  const int tr = tid >> 4, tc = tid & 15;   // 8 rows x 4 cols per thread
  float acc[8][4];
#pragma unroll
  for (int i=0;i<8;i++)
#pragma unroll
    for (int j=0;j<4;j++) acc[i][j] = sb[tc*4+j];
#pragma unroll 4
  for (int k=0;k<67;k++){
    float4 a0 = *(const float4*)&A [k][tr*8];
    float4 a1 = *(const float4*)&A [k][tr*8+4];
    float4 w  = *(const float4*)&Bw[k][tc*4];
    float av[8] = {a0.x,a0.y,a0.z,a0.w,a1.x,a1.y,a1.z,a1.w};
#pragma unroll
    for (int i=0;i<8;i++){
      acc[i][0]=fmaf(av[i],w.x,acc[i][0]);
      acc[i][1]=fmaf(av[i],w.y,acc[i][1]);
      acc[i][2]=fmaf(av[i],w.z,acc[i][2]);
      acc[i][3]=fmaf(av[i],w.w,acc[i][3]);
    }
  }
#pragma unroll
  for (int i=0;i<8;i++){
    uint2 v;
    v.x = (uint)f2bf(acc[i][0]) | ((uint)f2bf(acc[i][1])<<16);
    v.y = (uint)f2bf(acc[i][2]) | ((uint)f2bf(acc[i][3])<<16);
    *(uint2*)(x1 + ((rbase + tr*8 + i) << 6) + tc*4) = v;
  }
}

// ---------- convg64 (conv1): BN+ReLU on read, 128x64 tile, K=64, acc 8x4 ----------
__global__ __launch_bounds__(256, 2) void convg64_kernel(const ushort* __restrict__ xin,
                                                         const float* __restrict__ Sv,
                                                         const float* __restrict__ SSv,
                                                         const float* __restrict__ gg,
                                                         const float* __restrict__ be,
                                                         const float* __restrict__ W,
                                                         const float* __restrict__ bias,
                                                         ushort* __restrict__ xout){
  __shared__ float A [64][132];    // [k][row] 33.8 KB
  __shared__ float Bw[64][68];     // [k][out] 17.4 KB
  __shared__ float sc[64], sh[64], sb[64];
  const int tid = threadIdx.x;
  if (tid < 64){
    int c = tid;
    float mean = Sv[c]*INV_CNT;
    float var  = fmaf(-mean, mean, SSv[c]*INV_CNT);
    float is   = rsqrtf(var + 1e-5f);
    float scv  = gg[c]*is;
    sc[c] = scv; sh[c] = fmaf(-mean, scv, be[c]);
    sb[c] = bias[c];
  }
  {
    const int o  = tid & 63;
    const int kq = tid >> 6;          // 0..3, 16 k each
    const float* wrow = W + (size_t)o*64 + kq*16;
#pragma unroll
    for (int q=0;q<4;q++){
      float4 wv = *(const float4*)(wrow + q*4);
      int k = kq*16 + q*4;
      Bw[k+0][o]=wv.x; Bw[k+1][o]=wv.y; Bw[k+2][o]=wv.z; Bw[k+3][o]=wv.w;
    }
  }
  __syncthreads();                    // sc/sh ready for A fill
  const size_t rbase = (size_t)blockIdx.x * 128;
  {
    const int r  = tid & 127;
    const int kh = tid >> 7;          // which 32-k half
    const uint4* src = (const uint4*)(xin + ((rbase + r) << 6) + kh*32);
#pragma unroll
    for (int g=0; g<4; g++){
      uint4 v = src[g];
      uint d[4] = {v.x,v.y,v.z,v.w};
#pragma unroll
      for (int q=0;q<4;q++){
        int k = kh*32 + g*8 + 2*q;
        float a0 = bf2f(d[q] & 0xffffu), a1 = bf2f(d[q] >> 16);
        A[k+0][r] = fmaxf(fmaf(a0, sc[k+0], sh[k+0]), 0.f);
        A[k+1][r] = fmaxf(fmaf(a1, sc[k+1], sh[k+1]), 0.f);
      }
    }
  }
  __syncthreads();
  const int tr = tid >> 4, tc = tid & 15;
  float acc[8][4];
#pragma unroll
  for (int i=0;i<8;i++)
#pragma unroll
    for (int j=0;j<4;j++) acc[i][j] = sb[tc*4+j];
#pragma unroll 4
  for (int k=0;k<64;k++){
    float4 a0 = *(const float4*)&A [k][tr*8];
    float4 a1 = *(const float4*)&A [k][tr*8+4];
    float4 w  = *(const float4*)&Bw[k][tc*4];
    float av[8] = {a0.x,a0.y,a0.z,a0.w,a1.x,a1.y,a1.z,a1.w};
#pragma unroll
    for (int i=0;i<8;i++){
      acc[i][0]=fmaf(av[i],w.x,acc[i][0]);
      acc[i][1]=fmaf(av[i],w.y,acc[i][1]);
      acc[i][2]=fmaf(av[i],w.z,acc[i][2]);
      acc[i][3]=fmaf(av[i],w.w,acc[i][3]);
    }
  }
#pragma unroll
  for (int i=0;i<8;i++){
    uint2 v;
    v.x = (uint)f2bf(acc[i][0]) | ((uint)f2bf(acc[i][1])<<16);
    v.y = (uint)f2bf(acc[i][2]) | ((uint)f2bf(acc[i][3])<<16);
    *(uint2*)(xout + ((rbase + tr*8 + i) << 6) + tc*4) = v;
  }
}

// ---------- convg128 (conv2): BN+ReLU on read, 128x128 tile, K=64, acc 8x8 ----------
__global__ __launch_bounds__(256, 2) void convg128_kernel(const ushort* __restrict__ xin,
                                                          const float* __restrict__ Sv,
                                                          const float* __restrict__ SSv,
                                                          const float* __restrict__ gg,
                                                          const float* __restrict__ be,
                                                          const float* __restrict__ W,
                                                          const float* __restrict__ bias,
                                                          ushort* __restrict__ xout){
  __shared__ float A [64][132];    // [k][row] 33.8 KB
  __shared__ float Bw[64][132];    // [k][out] 33.8 KB (128 used)
  __shared__ float sc[64], sh[64], sb[128];
  const int tid = threadIdx.x;
  if (tid < 64){
    int c = tid;
    float mean = Sv[c]*INV_CNT;
    float var  = fmaf(-mean, mean, SSv[c]*INV_CNT);
    float is   = rsqrtf(var + 1e-5f);
    float scv  = gg[c]*is;
    sc[c] = scv; sh[c] = fmaf(-mean, scv, be[c]);
  }
  if (tid < 128) sb[tid] = bias[tid];
  {
    const int o  = tid & 127;
    const int kh = tid >> 7;          // 0/1, 32 k each
    const float* wrow = W + (size_t)o*64 + kh*32;
#pragma unroll
    for (int q=0;q<8;q++){
      float4 wv = *(const float4*)(wrow + q*4);
      int k = kh*32 + q*4;
      Bw[k+0][o]=wv.x; Bw[k+1][o]=wv.y; Bw[k+2][o]=wv.z; Bw[k+3][o]=wv.w;
    }
  }
  __syncthreads();                    // sc/sh ready for A fill
  const size_t rbase = (size_t)blockIdx.x * 128;
  {
    const int r  = tid & 127;
    const int kh = tid >> 7;
    const uint4* src = (const uint4*)(xin + ((rbase + r) << 6) + kh*32);
#pragma unroll
    for (int g=0; g<4; g++){
      uint4 v = src[g];
      uint d[4] = {v.x,v.y,v.z,v.w};
#pragma unroll
      for (int q=0;q<4;q++){
        int k = kh*32 + g*8 + 2*q;
        float a0 = bf2f(d[q] & 0xffffu), a1 = bf2f(d[q] >> 16);
        A[k+0][r] = fmaxf(fmaf(a0, sc[k+0], sh[k+0]), 0.f);
        A[k+1][r] = fmaxf(fmaf(a1, sc[k+1], sh[k+1]), 0.f);
      }
    }
  }
  __syncthreads();
  const int tr = tid >> 4, tc = tid & 15;   // 8 rows x 8 cols per thread
  float acc[8][8];
#pragma unroll
  for (int i=0;i<8;i++)
#pragma unroll
    for (int j=0;j<8;j++) acc[i][j] = sb[tc*8+j];
#pragma unroll 2
  for (int k=0;k<64;k++){
    float4 a0 = *(const float4*)&A [k][tr*8];
    float4 a1 = *(const float4*)&A [k][tr*8+4];
    float4 w0 = *(const float4*)&Bw[k][tc*8];
    float4 w1 = *(const float4*)&Bw[k][tc*8+4];
    float av[8] = {a0.x,a0.y,a0.z,a0.w,a1.x,a1.y,a1.z,a1.w};
    float wv[8] = {w0.x,w0.y,w0.z,w0.w,w1.x,w1.y,w1.z,w1.w};
#pragma unroll
    for (int i=0;i<8;i++)
#pragma unroll
      for (int j=0;j<8;j++)
        acc[i][j] = fmaf(av[i], wv[j], acc[i][j]);
  }
#pragma unroll
  for (int i=0;i<8;i++){
    uint4 v;
    v.x = (uint)f2bf(acc[i][0]) | ((uint)f2bf(acc[i][1])<<16);
    v.y = (uint)f2bf(acc[i][2]) | ((uint)f2bf(acc[i][3])<<16);
    v.z = (uint)f2bf(acc[i][4]) | ((uint)f2bf(acc[i][5])<<16);
    v.w = (uint)f2bf(acc[i][6]) | ((uint)f2bf(acc[i][7])<<16);
    *(uint4*)(xout + ((rbase + tr*8 + i) << 7) + tc*8) = v;
  }
}

// ---------- stats: per-channel sum & sumsq, vectorized 8 ch/thread ----------
template<int C>
__global__ __launch_bounds__(256) void stats_kernel(const ushort* __restrict__ x,
                                                    float* __restrict__ S,
                                                    float* __restrict__ SS){
  constexpr int GRP = C/8;
  constexpr int RL  = 256/GRP;
  const int cg = threadIdx.x % GRP;
  const int rl = threadIdx.x / GRP;
  const int rows_per_block = NROWS / 1024;   // grid = 1024
  const int r0 = blockIdx.x * rows_per_block;
  float s[8], ss[8];
#pragma unroll
  for (int j=0;j<8;j++){ s[j]=0.f; ss[j]=0.f; }
  for (int r = r0 + rl; r < r0 + rows_per_block; r += RL){
    uint4 v = *(const uint4*)(x + (size_t)r*C + cg*8);
    uint d[4] = {v.x, v.y, v.z, v.w};
#pragma unroll
    for (int q=0;q<4;q++){
      float a0 = bf2f(d[q] & 0xffffu), a1 = bf2f(d[q] >> 16);
      s[2*q]   += a0; ss[2*q]   = fmaf(a0, a0, ss[2*q]);
      s[2*q+1] += a1; ss[2*q+1] = fmaf(a1, a1, ss[2*q+1]);
    }
  }
  __shared__ float ls[256][8], lss[256][8];
#pragma unroll
  for (int j=0;j<8;j++){ ls[threadIdx.x][j]=s[j]; lss[threadIdx.x][j]=ss[j]; }
  __syncthreads();
  if (threadIdx.x < C){
    const int grp = threadIdx.x >> 3, j = threadIdx.x & 7;
    float a = 0.f, q2 = 0.f;
#pragma unroll
    for (int q = 0; q < RL; q++){ a += ls[q*GRP + grp][j]; q2 += lss[q*GRP + grp][j]; }
    atomicAdd(&S[threadIdx.x], a); atomicAdd(&SS[threadIdx.x], q2);
  }
}

// ---------- BN2+ReLU + maxpool over K ----------
__global__ __launch_bounds__(256) void maxpool_kernel(const ushort* __restrict__ x3,
                                                      const float* __restrict__ S2,
                                                      const float* __restrict__ SS2,
                                                      const float* __restrict__ g2,
                                                      const float* __restrict__ be2,
                                                      float* __restrict__ outp){
  const int lane = threadIdx.x & 63, wv = threadIdx.x >> 6;
  const int bm = blockIdx.x*4 + wv;           // 16384 (b,m) groups
  const int c0 = lane*2, c1 = c0+1;
  float mean0 = S2[c0]*INV_CNT;
  float var0  = fmaf(-mean0, mean0, SS2[c0]*INV_CNT);
  float s0 = g2[c0]*rsqrtf(var0+1e-5f);
  float h0 = fmaf(-mean0, s0, be2[c0]);
  float mean1 = S2[c1]*INV_CNT;
  float var1  = fmaf(-mean1, mean1, SS2[c1]*INV_CNT);
  float s1 = g2[c1]*rsqrtf(var1+1e-5f);
  float h1 = fmaf(-mean1, s1, be2[c1]);
  const uint* rb = (const uint*)(x3 + (size_t)bm*K_SMP*128);
  float mx0 = 0.f, mx1 = 0.f;                 // relu floor
#pragma unroll
  for (int k=0;k<K_SMP;k++){
    uint v = rb[k*64 + lane];
    float a0 = bf2f(v & 0xffffu), a1 = bf2f(v >> 16);
    mx0 = fmaxf(mx0, fmaxf(fmaf(a0, s0, h0), 0.f));
    mx1 = fmaxf(mx1, fmaxf(fmaf(a1, s1, h1), 0.f));
  }
  float2* o2 = (float2*)(outp + (size_t)bm*128);
  o2[lane] = make_float2(mx0, mx1);
}

// ---------- launch ----------
extern "C" void kernel_launch(void* const* d_in, const int* in_sizes, int n_in,
                              void* d_out, int out_size, void* d_ws, size_t ws_size,
                              hipStream_t stream){
  const float* xyz    = (const float*)d_in[0];
  const float* points = (const float*)d_in[1];
  const float* w0  = (const float*)d_in[2];
  const float* b0  = (const float*)d_in[3];
  const float* g0  = (const float*)d_in[4];
  const float* be0 = (const float*)d_in[5];
  const float* w1  = (const float*)d_in[6];
  const float* b1  = (const float*)d_in[7];
  const float* g1  = (const float*)d_in[8];
  const float* be1 = (const float*)d_in[9];
  const float* w2  = (const float*)d_in[10];
  const float* b2  = (const float*)d_in[11];
  const float* g2  = (const float*)d_in[12];
  const float* be2 = (const float*)d_in[13];

  float* out      = (float*)d_out;
  float* newxyz   = out;                        // [16,1024,3]
  float* outp     = out + (size_t)B_SZ*M_PTS*3; // [16,1024,128]

  char* ws = (char*)d_ws;
  int*   gidx  = (int*)ws;
  float* stats = (float*)(ws + (2u<<20));
  float* S0 = stats,      *SS0 = stats+64;
  float* S1 = stats+128,  *SS1 = stats+192;
  float* S2 = stats+256,  *SS2 = stats+384;
  ushort* x1 = (ushort*)(ws + (4u<<20));
  ushort* x3 = (ushort*)(ws + (4u<<20));
  ushort* x2 = (ushort*)(ws + (4u<<20) + 134217728u);

  hipMemsetAsync(stats, 0, 512*sizeof(float), stream);
  fps_kernel  <<<B_SZ, 512, 0, stream>>>(xyz, newxyz);
  ballq_kernel<<<1024, 256, 0, stream>>>(xyz, newxyz, gidx);
  conv0_kernel<<<NROWS/128, 256, 0, stream>>>(xyz, points, newxyz, gidx, w0, b0, x1);
  stats_kernel<64><<<1024, 256, 0, stream>>>(x1, S0, SS0);
  convg64_kernel<<<NROWS/128, 256, 0, stream>>>(x1, S0, SS0, g0, be0, w1, b1, x2);
  stats_kernel<64><<<1024, 256, 0, stream>>>(x2, S1, SS1);
  convg128_kernel<<<NROWS/128, 256, 0, stream>>>(x2, S1, SS1, g1, be1, w2, b2, x3);
  stats_kernel<128><<<1024, 256, 0, stream>>>(x3, S2, SS2);
  maxpool_kernel<<<NROWS/128, 256, 0, stream>>>(x3, S2, SS2, g2, be2, outp);
}